// Round 1
// baseline (416.003 us; speedup 1.0000x reference)
//
#include <hip/hip_runtime.h>
#include <hip/hip_bf16.h>

#define N_NODES 40000
#define N_EDGES 640000
#define HIDDEN  128
#define NUM_RBF 50

typedef __attribute__((ext_vector_type(8))) short bf16x8;
typedef __attribute__((ext_vector_type(4))) float f32x4;

__device__ __forceinline__ short f2bf(float f) {
  __hip_bfloat16 h = __float2bfloat16(f);
  return (short)__builtin_bit_cast(unsigned short, h);
}

__device__ __forceinline__ float fast_tanh(float x) {
  // tanh(x) = 1 - 2/(exp(2x)+1); exact at +-inf, ~1ulp via v_exp/v_rcp
  float e = __expf(2.0f * x);
  return 1.0f - 2.0f * __builtin_amdgcn_rcpf(e + 1.0f);
}

__device__ __forceinline__ f32x4 mfma16(bf16x8 a, bf16x8 b, f32x4 c) {
  return __builtin_amdgcn_mfma_f32_16x16x32_bf16(a, b, c, 0, 0, 0);
}

__device__ __forceinline__ bf16x8 load8_f32_bf16(const float* p) {
  const float4 v0 = ((const float4*)p)[0];
  const float4 v1 = ((const float4*)p)[1];
  bf16x8 r;
  r[0] = f2bf(v0.x); r[1] = f2bf(v0.y); r[2] = f2bf(v0.z); r[3] = f2bf(v0.w);
  r[4] = f2bf(v1.x); r[5] = f2bf(v1.y); r[6] = f2bf(v1.z); r[7] = f2bf(v1.w);
  return r;
}

// ---------------- kernel 1: h = x @ W_in  (+ zero agg) ----------------
__global__ __launch_bounds__(256) void hproj_kernel(
    const float* __restrict__ x, const float* __restrict__ W_in,
    float* __restrict__ h, float* __restrict__ agg)
{
  __shared__ __align__(16) unsigned short sWt[128 * 136]; // W_in^T, bf16, pad 8
  const int tid = threadIdx.x, wave = tid >> 6, lane = tid & 63;
  const int ln = lane & 15, grp = lane >> 4;
  const int r0 = blockIdx.x * 64;

  for (int idx = tid; idx < 128 * 128; idx += 256) {
    int k = idx >> 7, c = idx & 127;
    sWt[c * 136 + k] = f2bf(W_in[idx]);
  }
  // zero this block's agg rows
  {
    f32x4 z = {0.f, 0.f, 0.f, 0.f};
    f32x4* aggv = (f32x4*)(agg + (size_t)r0 * 128);
    for (int idx = tid; idx < 64 * 128 / 4; idx += 256) aggv[idx] = z;
  }
  __syncthreads();

  const size_t r = (size_t)r0 + wave * 16 + ln;
  f32x4 acc[8];
#pragma unroll
  for (int ct = 0; ct < 8; ++ct) acc[ct] = (f32x4){0.f, 0.f, 0.f, 0.f};
#pragma unroll
  for (int ks = 0; ks < 4; ++ks) {
    bf16x8 a = load8_f32_bf16(&x[r * 128 + ks * 32 + grp * 8]);
#pragma unroll
    for (int ct = 0; ct < 8; ++ct) {
      bf16x8 b = *(const bf16x8*)&sWt[(ct * 16 + ln) * 136 + ks * 32 + grp * 8];
      acc[ct] = mfma16(a, b, acc[ct]);
    }
  }
#pragma unroll
  for (int ct = 0; ct < 8; ++ct) {
#pragma unroll
    for (int i = 0; i < 4; ++i) {
      h[(size_t)(r0 + wave * 16 + grp * 4 + i) * 128 + ct * 16 + ln] = acc[ct][i];
    }
  }
}

// ---------------- kernel 2: edge filter + gather/scatter ----------------
__global__ __launch_bounds__(256, 2) void edge_kernel(
    const float* __restrict__ edge_attr,
    const int*   __restrict__ edge_index,
    const float* __restrict__ edge_weight,
    const float* __restrict__ W_f1, const float* __restrict__ b_f1,
    const float* __restrict__ W_f2, const float* __restrict__ b_f2,
    const float* __restrict__ h, float* __restrict__ agg)
{
  __shared__ __align__(16) unsigned short sW1t[128 * 72];   // W_f1^T, K padded 50->64, +8
  __shared__ __align__(16) unsigned short sW2t[128 * 136];  // W_f2^T, +8
  __shared__ __align__(16) unsigned short sT[64 * 136];     // A-tile then tanh output T
  __shared__ float sb1[128], sb2[128], sC[64];
  __shared__ int sSrc[64], sDst[64];

  const int tid = threadIdx.x, wave = tid >> 6, lane = tid & 63;
  const int ln = lane & 15, grp = lane >> 4;

  // one-time weight staging (persistent block)
  for (int idx = tid; idx < 128 * 64; idx += 256) {
    int k = idx >> 7, c = idx & 127;
    sW1t[c * 72 + k] = (k < NUM_RBF) ? f2bf(W_f1[k * 128 + c]) : (short)0;
  }
  for (int idx = tid; idx < 128 * 128; idx += 256) {
    int k = idx >> 7, c = idx & 127;
    sW2t[c * 136 + k] = f2bf(W_f2[idx]);
  }
  if (tid < 128) { sb1[tid] = b_f1[tid]; sb2[tid] = b_f2[tid]; }

  const int nTiles = N_EDGES / 64;
  for (int tile = blockIdx.x; tile < nTiles; tile += gridDim.x) {
    const int e0 = tile * 64;
    // stage A (edge_attr tile) into sT rows, bf16, zero-pad k in [50,64)
    for (int idx = tid; idx < 64 * NUM_RBF; idx += 256) {
      int e = idx / NUM_RBF, k = idx - e * NUM_RBF;
      sT[e * 136 + k] = f2bf(edge_attr[(size_t)e0 * NUM_RBF + idx]);
    }
    for (int idx = tid; idx < 64 * 14; idx += 256) {
      int e = idx / 14, k = NUM_RBF + (idx - (idx / 14) * 14);
      sT[e * 136 + k] = 0;
    }
    if (tid < 64) {
      int e = e0 + tid;
      sC[tid] = 0.5f * (__cosf(edge_weight[e] * 0.31415926535f) + 1.0f);
      sSrc[tid] = edge_index[e];
      sDst[tid] = edge_index[N_EDGES + e];
    }
    __syncthreads();

    const int erow = wave * 16 + ln;
    bf16x8 a0 = *(const bf16x8*)&sT[erow * 136 + grp * 8];
    bf16x8 a1 = *(const bf16x8*)&sT[erow * 136 + 32 + grp * 8];
    __syncthreads();  // everyone's A-frags in regs before sT is overwritten

    // GEMM1: T = tanh(A @ W1 + b1)
    f32x4 acc[8];
#pragma unroll
    for (int ct = 0; ct < 8; ++ct) {
      f32x4 z = {0.f, 0.f, 0.f, 0.f};
      int c = ct * 16 + ln;
      bf16x8 b0 = *(const bf16x8*)&sW1t[c * 72 + grp * 8];
      bf16x8 b1 = *(const bf16x8*)&sW1t[c * 72 + 32 + grp * 8];
      z = mfma16(a0, b0, z);
      z = mfma16(a1, b1, z);
      acc[ct] = z;
    }
#pragma unroll
    for (int ct = 0; ct < 8; ++ct) {
      int c = ct * 16 + ln;
      float bias = sb1[c];
#pragma unroll
      for (int i = 0; i < 4; ++i) {
        int el = wave * 16 + grp * 4 + i;
        sT[el * 136 + c] = f2bf(fast_tanh(acc[ct][i] + bias));
      }
    }
    __syncthreads();

    // GEMM2: Wf = (T @ W2 + b2) * C ; then msg/scatter
    bf16x8 af[4];
#pragma unroll
    for (int ks = 0; ks < 4; ++ks)
      af[ks] = *(const bf16x8*)&sT[erow * 136 + ks * 32 + grp * 8];
    f32x4 acc2[8];
#pragma unroll
    for (int ct = 0; ct < 8; ++ct) {
      f32x4 z = {0.f, 0.f, 0.f, 0.f};
      int c = ct * 16 + ln;
#pragma unroll
      for (int ks = 0; ks < 4; ++ks) {
        bf16x8 b = *(const bf16x8*)&sW2t[c * 136 + ks * 32 + grp * 8];
        z = mfma16(af[ks], b, z);
      }
      acc2[ct] = z;
    }
#pragma unroll
    for (int ct = 0; ct < 8; ++ct) {
      int c = ct * 16 + ln;
      float bias = sb2[c];
#pragma unroll
      for (int i = 0; i < 4; ++i) {
        int el = wave * 16 + grp * 4 + i;
        float wf = (acc2[ct][i] + bias) * sC[el];
        float msg = h[(size_t)sSrc[el] * 128 + c] * wf;
        atomicAdd(&agg[(size_t)sDst[el] * 128 + c], msg);
      }
    }
    __syncthreads();  // protect sT/sC/sSrc/sDst before next tile staging
  }
}

// ---------------- kernel 3: out = tanh(agg@W_out+b_out) @ W_lin + b_lin ----------------
__global__ __launch_bounds__(256) void tail_kernel(
    const float* __restrict__ agg,
    const float* __restrict__ W_out, const float* __restrict__ b_out,
    const float* __restrict__ W_lin, const float* __restrict__ b_lin,
    float* __restrict__ out)
{
  __shared__ __align__(16) unsigned short sWo[128 * 136];
  __shared__ __align__(16) unsigned short sWl[128 * 136];
  __shared__ __align__(16) unsigned short sT[64 * 136];
  __shared__ float sbo[128], sbl[128];
  const int tid = threadIdx.x, wave = tid >> 6, lane = tid & 63;
  const int ln = lane & 15, grp = lane >> 4;
  const int r0 = blockIdx.x * 64;

  for (int idx = tid; idx < 128 * 128; idx += 256) {
    int k = idx >> 7, c = idx & 127;
    sWo[c * 136 + k] = f2bf(W_out[idx]);
    sWl[c * 136 + k] = f2bf(W_lin[idx]);
  }
  if (tid < 128) { sbo[tid] = b_out[tid]; sbl[tid] = b_lin[tid]; }
  __syncthreads();

  const size_t r = (size_t)r0 + wave * 16 + ln;
  f32x4 acc[8];
#pragma unroll
  for (int ct = 0; ct < 8; ++ct) acc[ct] = (f32x4){0.f, 0.f, 0.f, 0.f};
#pragma unroll
  for (int ks = 0; ks < 4; ++ks) {
    bf16x8 a = load8_f32_bf16(&agg[r * 128 + ks * 32 + grp * 8]);
#pragma unroll
    for (int ct = 0; ct < 8; ++ct) {
      bf16x8 b = *(const bf16x8*)&sWo[(ct * 16 + ln) * 136 + ks * 32 + grp * 8];
      acc[ct] = mfma16(a, b, acc[ct]);
    }
  }
#pragma unroll
  for (int ct = 0; ct < 8; ++ct) {
    int c = ct * 16 + ln;
    float bias = sbo[c];
#pragma unroll
    for (int i = 0; i < 4; ++i) {
      int rl = wave * 16 + grp * 4 + i;
      sT[rl * 136 + c] = f2bf(fast_tanh(acc[ct][i] + bias));
    }
  }
  __syncthreads();

  bf16x8 af[4];
#pragma unroll
  for (int ks = 0; ks < 4; ++ks)
    af[ks] = *(const bf16x8*)&sT[(wave * 16 + ln) * 136 + ks * 32 + grp * 8];
  f32x4 acc2[8];
#pragma unroll
  for (int ct = 0; ct < 8; ++ct) {
    f32x4 z = {0.f, 0.f, 0.f, 0.f};
    int c = ct * 16 + ln;
#pragma unroll
    for (int ks = 0; ks < 4; ++ks) {
      bf16x8 b = *(const bf16x8*)&sWl[c * 136 + ks * 32 + grp * 8];
      z = mfma16(af[ks], b, z);
    }
    acc2[ct] = z;
  }
#pragma unroll
  for (int ct = 0; ct < 8; ++ct) {
    int c = ct * 16 + ln;
    float bias = sbl[c];
#pragma unroll
    for (int i = 0; i < 4; ++i) {
      out[(size_t)(r0 + wave * 16 + grp * 4 + i) * 128 + c] = acc2[ct][i] + bias;
    }
  }
}

extern "C" void kernel_launch(void* const* d_in, const int* in_sizes, int n_in,
                              void* d_out, int out_size, void* d_ws, size_t ws_size,
                              hipStream_t stream) {
  const float* x     = (const float*)d_in[0];
  const int*   ei    = (const int*)d_in[1];     // [2, E] int32 (JAX default x64-off)
  const float* ew    = (const float*)d_in[2];
  const float* ea    = (const float*)d_in[3];
  const float* W_f1  = (const float*)d_in[4];
  const float* b_f1  = (const float*)d_in[5];
  const float* W_f2  = (const float*)d_in[6];
  const float* b_f2  = (const float*)d_in[7];
  const float* W_in  = (const float*)d_in[8];
  const float* W_out = (const float*)d_in[9];
  const float* b_out = (const float*)d_in[10];
  const float* W_lin = (const float*)d_in[11];
  const float* b_lin = (const float*)d_in[12];

  float* h   = (float*)d_ws;                          // 40000*128 f32 = 20.48 MB
  float* agg = h + (size_t)N_NODES * HIDDEN;          // 20.48 MB

  hproj_kernel<<<N_NODES / 64, 256, 0, stream>>>(x, W_in, h, agg);
  edge_kernel<<<512, 256, 0, stream>>>(ea, ei, ew, W_f1, b_f1, W_f2, b_f2, h, agg);
  tail_kernel<<<N_NODES / 64, 256, 0, stream>>>(agg, W_out, b_out, W_lin, b_lin, (float*)d_out);
}